// Round 14
// baseline (609.152 us; speedup 1.0000x reference)
//
#include <hip/hip_runtime.h>
#include <hip/hip_bf16.h>
#include <stdint.h>

#define IN_F   4096
#define OUT_F  11008
#define M_DIM  8192          // B*S

// ------- 256x128 block as 2 waves of 128x128, int8, triple-buffered -------
#define BM 256
#define BN 128
#define TM (M_DIM / BM)        // 32
#define TN (OUT_F / BN)        // 86
#define NWG (TM * TN)          // 2752
#define KT (IN_F / 64)         // 64 K-tiles of 64 i8
#define KC (IN_F / 16)         // 256 16-B chunks per row
#define TILE_B 24576           // per-buffer: A 16 KB + B 8 KB
#define B_OFF  16384

typedef __attribute__((ext_vector_type(4))) int   int32x4;
typedef __attribute__((ext_vector_type(8))) short short8;
typedef __attribute__((ext_vector_type(4))) float f32x4;

union Pack8 { __bf16 h[8]; uint4 u; };
union PackI { char c[16]; ::int4 v; };

__device__ inline uint4 pack8_f(float4 f0, float4 f1) {
    Pack8 o;
    o.h[0] = (__bf16)f0.x; o.h[1] = (__bf16)f0.y;
    o.h[2] = (__bf16)f0.z; o.h[3] = (__bf16)f0.w;
    o.h[4] = (__bf16)f1.x; o.h[5] = (__bf16)f1.y;
    o.h[6] = (__bf16)f1.z; o.h[7] = (__bf16)f1.w;
    return o.u;
}

__device__ inline uint4 dequant8(int4 v, float s, float zb) {
    Pack8 o;
    int pv[4] = {v.x, v.y, v.z, v.w};
#pragma unroll
    for (int j = 0; j < 4; ++j) {
        o.h[2 * j]     = (__bf16)fmaf((float)(pv[j] & 15), s, zb);
        o.h[2 * j + 1] = (__bf16)fmaf((float)((pv[j] >> 4) & 15), s, zb);
    }
    return o.u;
}

#define GLOAD_LDS16(g, l)                                                     \
    __builtin_amdgcn_global_load_lds(                                         \
        (const __attribute__((address_space(1))) void*)(g),                   \
        (__attribute__((address_space(3))) void*)(l), 16, 0, 0)

#define BAR()   __builtin_amdgcn_s_barrier()
#define SBAR0() __builtin_amdgcn_sched_barrier(0)
#define VMW(n)  asm volatile("s_waitcnt vmcnt(" #n ")" ::: "memory")

// ---------- preprocessing: x fp32 -> i8 with per-row absmax scale (proven) ----------
__global__ __launch_bounds__(256) void quant_x_kernel(const float* __restrict__ x,
        char* __restrict__ xq, float* __restrict__ srow) {
    const int row = blockIdx.x;
    const int t   = threadIdx.x;
    const float4* xr = (const float4*)(x + (size_t)row * IN_F) + t * 4;
    float4 v[4];
    float am = 0.f;
#pragma unroll
    for (int j = 0; j < 4; ++j) {
        v[j] = xr[j];
        am = fmaxf(am, fmaxf(fmaxf(fabsf(v[j].x), fabsf(v[j].y)),
                             fmaxf(fabsf(v[j].z), fabsf(v[j].w))));
    }
#pragma unroll
    for (int off = 32; off; off >>= 1) am = fmaxf(am, __shfl_xor(am, off, 64));
    __shared__ float wm4[4];
    if ((t & 63) == 0) wm4[t >> 6] = am;
    __syncthreads();
    am = fmaxf(fmaxf(wm4[0], wm4[1]), fmaxf(wm4[2], wm4[3]));
    const float qs = am > 0.f ? 127.f / am : 0.f;
    if (t == 0) srow[row] = am > 0.f ? am * (1.f / 127.f) : 0.f;
    PackI o;
#pragma unroll
    for (int j = 0; j < 4; ++j) {
        const float* f = (const float*)&v[j];
#pragma unroll
        for (int e = 0; e < 4; ++e) {
            float q = rintf(f[e] * qs);
            q = fminf(127.f, fmaxf(-127.f, q));
            o.c[j * 4 + e] = (char)(int)q;
        }
    }
    ((::int4*)(xq + (size_t)row * IN_F))[t] = o.v;
}

// ---------- preprocessing: packed int4 W -> i8 (q - zp, EXACT, proven) ----------
__global__ void deqw_i8_kernel(const int* __restrict__ pw, const int* __restrict__ zps,
                               char* __restrict__ wq, int nChunks) {
    int stride = gridDim.x * blockDim.x;
    for (int c = blockIdx.x * blockDim.x + threadIdx.x; c < nChunks; c += stride) {
        int row = c >> 8;          // 256 16-B chunks per row
        int cc  = c & 255;
        int zp  = zps[row];
        const ::int4* p = (const ::int4*)(pw + (size_t)row * (IN_F / 2) + cc * 8);
        ::int4 v0 = p[0], v1 = p[1];
        int pv[8] = {v0.x, v0.y, v0.z, v0.w, v1.x, v1.y, v1.z, v1.w};
        PackI o;
#pragma unroll
        for (int j = 0; j < 8; ++j) {
            o.c[2 * j]     = (char)((pv[j] & 15) - zp);
            o.c[2 * j + 1] = (char)(((pv[j] >> 4) & 15) - zp);
        }
        ((::int4*)wq)[c] = o.v;
    }
}

// ---------- the triple-buffered 256x128 i8 GEMM, 128x128 wave tiles ----------
// 128 threads = 2 waves; wave w owns rows [w*128, w*128+128) x all 128 cols.
// LDS per buffer (24 KB): A [256 rows][64 B] at [0,16K); B [128 rows][64 B] at
// [16K,24K). Slot swizzle (R8-proven): slot s of row r holds chunk s^((r>>1)&3);
// staging pre-swizzle (l&3)^((l>>3)&3) exact since per-wave row bases are
// 16-aligned. Staging: 12 gloads/thread/iter (A: 8 issues of 32 rows, B: 4).
// K-loop: stage kt+2 -> bufS; VMW(24) completes kt collectively (36 -> 24);
// BAR; 16 ds_read_b128 + 64 MFMA per wave; end-BAR = WAR fence.
__global__ __launch_bounds__(128, 1) void w4a16_gemm_i8(
    const uint4* __restrict__ xq4, const uint4* __restrict__ wq4,
    const float* __restrict__ srow, const float* __restrict__ scales,
    const float* __restrict__ bias, float* __restrict__ out) {

    extern __shared__ __align__(16) char smem[];   // 72 KiB (3 buffers)

    const int tid  = threadIdx.x;
    const int lane = tid & 63;
    const int w    = tid >> 6;     // 0..1 : wave = m-group of 128 rows

    // 2-D supertile: XCD (bid&7) owns tm in [4*xcd,4*xcd+4); 4x4 supertiles
    // across TN=86 (21 full col-groups + ragged 2). Bijective (R12-proven).
    const int bid = blockIdx.x;
    const int xcd = bid & 7;
    const int p   = bid >> 3;          // 0..343
    int tm, tn;
    if (p < 336) { int c = p >> 4, q = p & 15; tm = xcd * 4 + (q & 3); tn = c * 4 + (q >> 2); }
    else         { int q = p - 336;            tm = xcd * 4 + (q & 3); tn = 84 + (q >> 2); }
    const int bm0 = tm * BM;
    const int bn0 = tn * BN;

    // staging: issue i covers rows i*32 + w*16 + (lane>>2), slot lane&3,
    // source chunk csw; LDS dest = bufbase + i*2048 + w*1024 (+ lane*16)
    const int r4  = (w << 4) + (lane >> 2);            // 0..31
    const int csw = (lane & 3) ^ ((lane >> 3) & 3);
    const uint4* gA = xq4 + (size_t)(bm0 + r4) * KC + csw;
    const uint4* gB = wq4 + (size_t)(bn0 + r4) * KC + csw;
    const int wo = w << 10;

    int32x4 acc[8][8];
#pragma unroll
    for (int mi = 0; mi < 8; ++mi)
#pragma unroll
        for (int nj = 0; nj < 8; ++nj) acc[mi][nj] = {0, 0, 0, 0};

    // prologue: tiles 0,1 -> bufs 0,1 (24 loads); no gate (loop gate covers iter 0)
#pragma unroll
    for (int t = 0; t < 2; ++t) {
        char* bb = smem + t * TILE_B;
#pragma unroll
        for (int i = 0; i < 8; ++i)
            GLOAD_LDS16(gA + (size_t)(i * 32) * KC + t * 4, bb + i * 2048 + wo);
#pragma unroll
        for (int i = 0; i < 4; ++i)
            GLOAD_LDS16(gB + (size_t)(i * 32) * KC + t * 4, bb + B_OFF + i * 2048 + wo);
    }

    int bR = 0, bS = 2;   // read buffer, stage buffer
    for (int kt = 0; kt < KT; ++kt) {
        // stage tile kt+2 (wrapped trailing stages never read)
        const int tc = ((kt + 2) & (KT - 1)) * 4;
        {
            char* bb = smem + bS * TILE_B;
#pragma unroll
            for (int i = 0; i < 8; ++i)
                GLOAD_LDS16(gA + (size_t)(i * 32) * KC + tc, bb + i * 2048 + wo);
#pragma unroll
            for (int i = 0; i < 4; ++i)
                GLOAD_LDS16(gB + (size_t)(i * 32) * KC + tc, bb + B_OFF + i * 2048 + wo);
        }
        VMW(24); SBAR0(); BAR(); SBAR0();   // tile kt fully in bufR, collectively

        const char* base = smem + bR * TILE_B;
        int32x4 a[8], b[8];
#pragma unroll
        for (int mi = 0; mi < 8; ++mi) {
            int row = w * 128 + mi * 16 + (lane & 15);
            a[mi] = *(const int32x4*)(base + row * 64 +
                     (((lane >> 4) * 16) ^ (((row >> 1) & 3) << 4)));
        }
#pragma unroll
        for (int nj = 0; nj < 8; ++nj) {
            int row = nj * 16 + (lane & 15);
            b[nj] = *(const int32x4*)(base + B_OFF + row * 64 +
                     (((lane >> 4) * 16) ^ (((row >> 1) & 3) << 4)));
        }
        __builtin_amdgcn_s_setprio(1);
#pragma unroll
        for (int mi = 0; mi < 8; ++mi)
#pragma unroll
            for (int nj = 0; nj < 8; ++nj)
                acc[mi][nj] = __builtin_amdgcn_mfma_i32_16x16x64_i8(
                    a[mi], b[nj], acc[mi][nj], 0, 0, 0);
        __builtin_amdgcn_s_setprio(0);
        BAR();                              // WAR fence before bufR is re-staged

        bR = (bR == 2) ? 0 : bR + 1; bS = (bS == 2) ? 0 : bS + 1;
    }
    VMW(0);   // drain wrapped trailing stages before endpgm

    // ---- epilogue: out = i32_acc * srow[row] * scales[col] + bias[col] ----
    // C/D 16x16 layout (proven): col = lane&15, row = (lane>>4)*4 + rr
#pragma unroll
    for (int mi = 0; mi < 8; ++mi) {
        int row0 = bm0 + w * 128 + mi * 16 + (lane >> 4) * 4;
        float sr[4];
#pragma unroll
        for (int rr = 0; rr < 4; ++rr) sr[rr] = srow[row0 + rr];
#pragma unroll
        for (int nj = 0; nj < 8; ++nj) {
            int col  = bn0 + nj * 16 + (lane & 15);
            float sc = scales[col];
            float bv = bias[col];
#pragma unroll
            for (int rr = 0; rr < 4; ++rr)
                __builtin_nontemporal_store(
                    (float)acc[mi][nj][rr] * (sr[rr] * sc) + bv,
                    &out[(size_t)(row0 + rr) * OUT_F + col]);
        }
    }
}

// ---------- fallback (ws too small): reg-staged bf16 128^2 with inline dequant ----------
#define FBM 128
#define FBN 128
#define FTM (M_DIM / FBM)
#define FTN (OUT_F / FBN)
#define FNWG (FTM * FTN)

__global__ __launch_bounds__(256) void w4a16_gemm_fb(
    const float* __restrict__ xf,
    const int* __restrict__ pw,
    const float* __restrict__ scales, const int* __restrict__ zps,
    const float* __restrict__ bias, float* __restrict__ out) {

    __shared__ __align__(16) __bf16 As[FBM * 64];
    __shared__ __align__(16) __bf16 Bs[FBN * 64];

    const int tid  = threadIdx.x;
    const int lane = tid & 63;
    const int wid  = tid >> 6;
    const int wm   = wid >> 1;
    const int wn   = wid & 1;

    int orig = blockIdx.x;
    int wg   = (orig & 7) * (FNWG / 8) + (orig >> 3);
    const int bm0 = (wg / FTN) * FBM;
    const int bn0 = (wg % FTN) * FBN;

    f32x4 acc[4][4];
#pragma unroll
    for (int i = 0; i < 4; ++i)
#pragma unroll
        for (int j = 0; j < 4; ++j) acc[i][j] = {0.f, 0.f, 0.f, 0.f};

    for (int kt = 0; kt < IN_F / 64; ++kt) {
#pragma unroll
        for (int i = 0; i < 4; ++i) {
            int ci  = i * 256 + tid;
            int row = ci >> 3, c8 = ci & 7;
            const float4* pp = (const float4*)(xf + (size_t)(bm0 + row) * IN_F + kt * 64 + c8 * 8);
            uint4 d = pack8_f(pp[0], pp[1]);
            *(uint4*)((char*)As + row * 128 + ((c8 * 16) ^ ((row & 7) << 4))) = d;
        }
#pragma unroll
        for (int i = 0; i < 4; ++i) {
            int ci  = i * 256 + tid;
            int row = ci >> 3, c8 = ci & 7;
            int r    = bn0 + row;
            float s  = scales[r];
            float zb = -s * (float)zps[r];
            int4 v = *(const int4*)(pw + (size_t)r * (IN_F / 2) + kt * 32 + c8 * 4);
            uint4 d = dequant8(v, s, zb);
            *(uint4*)((char*)Bs + row * 128 + ((c8 * 16) ^ ((row & 7) << 4))) = d;
        }
        __syncthreads();

#pragma unroll
        for (int kk = 0; kk < 2; ++kk) {
            short8 a[4], b[4];
#pragma unroll
            for (int mi = 0; mi < 4; ++mi) {
                int row = wm * 64 + mi * 16 + (lane & 15);
                a[mi] = *(const short8*)((const char*)As + row * 128 +
                                         ((kk * 64 + (lane >> 4) * 16) ^ ((row & 7) << 4)));
            }
#pragma unroll
            for (int ni = 0; ni < 4; ++ni) {
                int row = wn * 64 + ni * 16 + (lane & 15);
                b[ni] = *(const short8*)((const char*)Bs + row * 128 +
                                         ((kk * 64 + (lane >> 4) * 16) ^ ((row & 7) << 4)));
            }
#pragma unroll
            for (int mi = 0; mi < 4; ++mi)
#pragma unroll
                for (int ni = 0; ni < 4; ++ni)
                    acc[mi][ni] = __builtin_amdgcn_mfma_f32_16x16x32_bf16(a[mi], b[ni], acc[mi][ni], 0, 0, 0);
        }
        __syncthreads();
    }

#pragma unroll
    for (int ni = 0; ni < 4; ++ni) {
        int col  = bn0 + wn * 64 + ni * 16 + (lane & 15);
        float bv = bias[col];
#pragma unroll
        for (int mi = 0; mi < 4; ++mi) {
            int row0 = bm0 + wm * 64 + mi * 16 + (lane >> 4) * 4;
#pragma unroll
            for (int r = 0; r < 4; ++r)
                out[(size_t)(row0 + r) * OUT_F + col] = acc[mi][ni][r] + bv;
        }
    }
}

extern "C" void kernel_launch(void* const* d_in, const int* in_sizes, int n_in,
                              void* d_out, int out_size, void* d_ws, size_t ws_size,
                              hipStream_t stream) {
    const float* x      = (const float*)d_in[0];
    const int* pw       = (const int*)d_in[1];
    const float* scales = (const float*)d_in[2];
    const int* zps      = (const int*)d_in[3];
    const float* bias   = (const float*)d_in[4];
    float* out          = (float*)d_out;

    const size_t xq_bytes = (size_t)M_DIM * IN_F;        // 32 MiB i8
    const size_t sr_bytes = 65536;                       // srow f32 + pad
    const size_t wq_bytes = (size_t)OUT_F * IN_F;        // ~43 MiB i8
    const bool predeq = ws_size >= xq_bytes + sr_bytes + wq_bytes;

    if (predeq) {
        char*  xq   = (char*)d_ws;
        float* srow = (float*)((char*)d_ws + xq_bytes);
        char*  wq   = (char*)d_ws + xq_bytes + sr_bytes;
        quant_x_kernel<<<dim3(M_DIM), dim3(256), 0, stream>>>(x, xq, srow);
        deqw_i8_kernel<<<dim3(2048), dim3(256), 0, stream>>>(pw, zps, wq, OUT_F * (IN_F / 16));
        (void)hipFuncSetAttribute((const void*)w4a16_gemm_i8,
                                  hipFuncAttributeMaxDynamicSharedMemorySize, 3 * TILE_B);
        w4a16_gemm_i8<<<dim3(NWG), dim3(128), 3 * TILE_B, stream>>>(
            (const uint4*)xq, (const uint4*)wq, srow, scales, bias, out);
    } else {
        w4a16_gemm_fb<<<dim3(FNWG), dim3(256), 0, stream>>>(x, pw, scales, zps, bias, out);
    }
}

// Round 15
// 433.977 us; speedup vs baseline: 1.4037x; 1.4037x over previous
//
#include <hip/hip_runtime.h>
#include <hip/hip_bf16.h>
#include <stdint.h>

#define IN_F   4096
#define OUT_F  11008
#define M_DIM  8192          // B*S

// ------- 256x128 block, 4 waves of 128x64, int8, triple-buffered single-phase -------
#define BM 256
#define BN 128
#define TM (M_DIM / BM)        // 32
#define TN (OUT_F / BN)        // 86
#define NWG (TM * TN)          // 2752 -> 10.75 rounds (2.3% tail)
#define KT (IN_F / 64)         // 64 K-tiles of 64 i8
#define KC (IN_F / 16)         // 256 16-B chunks per row
#define TILE_B 24576           // per-buffer: A 16 KB + B 8 KB
#define B_OFF  16384

typedef __attribute__((ext_vector_type(4))) int   int32x4;
typedef __attribute__((ext_vector_type(8))) short short8;
typedef __attribute__((ext_vector_type(4))) float f32x4;

union Pack8 { __bf16 h[8]; uint4 u; };
union PackI { char c[16]; ::int4 v; };

__device__ inline uint4 pack8_f(float4 f0, float4 f1) {
    Pack8 o;
    o.h[0] = (__bf16)f0.x; o.h[1] = (__bf16)f0.y;
    o.h[2] = (__bf16)f0.z; o.h[3] = (__bf16)f0.w;
    o.h[4] = (__bf16)f1.x; o.h[5] = (__bf16)f1.y;
    o.h[6] = (__bf16)f1.z; o.h[7] = (__bf16)f1.w;
    return o.u;
}

__device__ inline uint4 dequant8(int4 v, float s, float zb) {
    Pack8 o;
    int pv[4] = {v.x, v.y, v.z, v.w};
#pragma unroll
    for (int j = 0; j < 4; ++j) {
        o.h[2 * j]     = (__bf16)fmaf((float)(pv[j] & 15), s, zb);
        o.h[2 * j + 1] = (__bf16)fmaf((float)((pv[j] >> 4) & 15), s, zb);
    }
    return o.u;
}

#define GLOAD_LDS16(g, l)                                                     \
    __builtin_amdgcn_global_load_lds(                                         \
        (const __attribute__((address_space(1))) void*)(g),                   \
        (__attribute__((address_space(3))) void*)(l), 16, 0, 0)

#define BAR()   __builtin_amdgcn_s_barrier()
#define SBAR0() __builtin_amdgcn_sched_barrier(0)
#define VMW(n)  asm volatile("s_waitcnt vmcnt(" #n ")" ::: "memory")

// ---------- preprocessing: x fp32 -> i8 with per-row absmax scale (proven) ----------
__global__ __launch_bounds__(256) void quant_x_kernel(const float* __restrict__ x,
        char* __restrict__ xq, float* __restrict__ srow) {
    const int row = blockIdx.x;
    const int t   = threadIdx.x;
    const float4* xr = (const float4*)(x + (size_t)row * IN_F) + t * 4;
    float4 v[4];
    float am = 0.f;
#pragma unroll
    for (int j = 0; j < 4; ++j) {
        v[j] = xr[j];
        am = fmaxf(am, fmaxf(fmaxf(fabsf(v[j].x), fabsf(v[j].y)),
                             fmaxf(fabsf(v[j].z), fabsf(v[j].w))));
    }
#pragma unroll
    for (int off = 32; off; off >>= 1) am = fmaxf(am, __shfl_xor(am, off, 64));
    __shared__ float wm4[4];
    if ((t & 63) == 0) wm4[t >> 6] = am;
    __syncthreads();
    am = fmaxf(fmaxf(wm4[0], wm4[1]), fmaxf(wm4[2], wm4[3]));
    const float qs = am > 0.f ? 127.f / am : 0.f;
    if (t == 0) srow[row] = am > 0.f ? am * (1.f / 127.f) : 0.f;
    PackI o;
#pragma unroll
    for (int j = 0; j < 4; ++j) {
        const float* f = (const float*)&v[j];
#pragma unroll
        for (int e = 0; e < 4; ++e) {
            float q = rintf(f[e] * qs);
            q = fminf(127.f, fmaxf(-127.f, q));
            o.c[j * 4 + e] = (char)(int)q;
        }
    }
    ((::int4*)(xq + (size_t)row * IN_F))[t] = o.v;
}

// ---------- preprocessing: packed int4 W -> i8 (q - zp, EXACT, proven) ----------
__global__ void deqw_i8_kernel(const int* __restrict__ pw, const int* __restrict__ zps,
                               char* __restrict__ wq, int nChunks) {
    int stride = gridDim.x * blockDim.x;
    for (int c = blockIdx.x * blockDim.x + threadIdx.x; c < nChunks; c += stride) {
        int row = c >> 8;          // 256 16-B chunks per row
        int cc  = c & 255;
        int zp  = zps[row];
        const ::int4* p = (const ::int4*)(pw + (size_t)row * (IN_F / 2) + cc * 8);
        ::int4 v0 = p[0], v1 = p[1];
        int pv[8] = {v0.x, v0.y, v0.z, v0.w, v1.x, v1.y, v1.z, v1.w};
        PackI o;
#pragma unroll
        for (int j = 0; j < 8; ++j) {
            o.c[2 * j]     = (char)((pv[j] & 15) - zp);
            o.c[2 * j + 1] = (char)(((pv[j] >> 4) & 15) - zp);
        }
        ((::int4*)wq)[c] = o.v;
    }
}

// ---------- the triple-buffered 256x128 i8 GEMM, 128x64 wave tiles (R13, best) ----------
// LDS per buffer (24 KB): A [256 rows][64 B] at [0,16K); B [128 rows][64 B] at
// [16K,24K). Slot swizzle (R8-proven): slot s of row r holds chunk s^((r>>1)&3);
// staging source pre-swizzle (l&3)^((l>>3)&3) (16-row-aligned issue bases).
// K-loop: stage tile kt+2 -> bufS (6 gloads/thread: A x4, B x2); VMW(12)
// completes tile kt collectively (18 outstanding -> 12); BAR; reads (12 x b128)
// + 32 MFMA (compiler-interleaved); end-BAR = WAR fence.
__global__ __launch_bounds__(256, 2) void w4a16_gemm_i8(
    const uint4* __restrict__ xq4, const uint4* __restrict__ wq4,
    const float* __restrict__ srow, const float* __restrict__ scales,
    const float* __restrict__ bias, float* __restrict__ out) {

    extern __shared__ __align__(16) char smem[];   // 72 KiB (3 buffers)

    const int tid  = threadIdx.x;
    const int lane = tid & 63;
    const int wid  = tid >> 6;     // 0..3
    const int wm   = wid >> 1;     // 0..1 (m-group, 128 rows)
    const int wn   = wid & 1;      // 0..1 (n-group, 64 cols)

    // 2-D supertile: XCD (bid&7) owns tm in [4*xcd,4*xcd+4); 4x4 supertiles
    // across TN=86 (21 full col-groups + ragged 2). Bijective (R12-proven).
    const int bid = blockIdx.x;
    const int xcd = bid & 7;
    const int p   = bid >> 3;          // 0..343
    int tm, tn;
    if (p < 336) { int c = p >> 4, q = p & 15; tm = xcd * 4 + (q & 3); tn = c * 4 + (q >> 2); }
    else         { int q = p - 336;            tm = xcd * 4 + (q & 3); tn = 84 + (q >> 2); }
    const int bm0 = tm * BM;
    const int bn0 = tn * BN;

    // staging: issue i covers rows i*64 + wid*16 + (lane>>2), slot lane&3,
    // source chunk csw; LDS dest = bufbase + i*4096 + wid*1024 (+ lane*16 implicit)
    const int r4  = (wid << 4) + (lane >> 2);          // 0..63
    const int csw = (lane & 3) ^ ((lane >> 3) & 3);
    const uint4* gA = xq4 + (size_t)(bm0 + r4) * KC + csw;
    const uint4* gB = wq4 + (size_t)(bn0 + r4) * KC + csw;
    const int wo = wid << 10;

    int32x4 acc[8][4];
#pragma unroll
    for (int mi = 0; mi < 8; ++mi)
#pragma unroll
        for (int nj = 0; nj < 4; ++nj) acc[mi][nj] = {0, 0, 0, 0};

    // prologue: tiles 0,1 -> bufs 0,1 (12 loads)
#pragma unroll
    for (int t = 0; t < 2; ++t) {
        char* bb = smem + t * TILE_B;
#pragma unroll
        for (int i = 0; i < 4; ++i)
            GLOAD_LDS16(gA + (size_t)(i * 64) * KC + t * 4, bb + i * 4096 + wo);
#pragma unroll
        for (int i = 0; i < 2; ++i)
            GLOAD_LDS16(gB + (size_t)(i * 64) * KC + t * 4, bb + B_OFF + i * 4096 + wo);
    }

    int bR = 0, bS = 2;   // read buffer, stage buffer
    for (int kt = 0; kt < KT; ++kt) {
        // stage tile kt+2 (wrapped trailing stages never read)
        const int tc = ((kt + 2) & (KT - 1)) * 4;
        {
            char* bb = smem + bS * TILE_B;
#pragma unroll
            for (int i = 0; i < 4; ++i)
                GLOAD_LDS16(gA + (size_t)(i * 64) * KC + tc, bb + i * 4096 + wo);
#pragma unroll
            for (int i = 0; i < 2; ++i)
                GLOAD_LDS16(gB + (size_t)(i * 64) * KC + tc, bb + B_OFF + i * 4096 + wo);
        }
        VMW(12); SBAR0(); BAR(); SBAR0();   // tile kt fully in bufR, collectively

        const char* base = smem + bR * TILE_B;
        int32x4 a[8], b[4];
#pragma unroll
        for (int mi = 0; mi < 8; ++mi) {
            int row = wm * 128 + mi * 16 + (lane & 15);
            a[mi] = *(const int32x4*)(base + row * 64 +
                     (((lane >> 4) * 16) ^ (((row >> 1) & 3) << 4)));
        }
#pragma unroll
        for (int nj = 0; nj < 4; ++nj) {
            int row = wn * 64 + nj * 16 + (lane & 15);
            b[nj] = *(const int32x4*)(base + B_OFF + row * 64 +
                     (((lane >> 4) * 16) ^ (((row >> 1) & 3) << 4)));
        }
        __builtin_amdgcn_s_setprio(1);
#pragma unroll
        for (int mi = 0; mi < 8; ++mi)
#pragma unroll
            for (int nj = 0; nj < 4; ++nj)
                acc[mi][nj] = __builtin_amdgcn_mfma_i32_16x16x64_i8(
                    a[mi], b[nj], acc[mi][nj], 0, 0, 0);
        __builtin_amdgcn_s_setprio(0);
        BAR();                              // WAR fence before bufR is re-staged

        bR = (bR == 2) ? 0 : bR + 1; bS = (bS == 2) ? 0 : bS + 1;
    }
    VMW(0);   // drain wrapped trailing stages before endpgm

    // ---- epilogue: out = i32_acc * srow[row] * scales[col] + bias[col] ----
    // C/D 16x16 layout (proven): col = lane&15, row = (lane>>4)*4 + rr
#pragma unroll
    for (int mi = 0; mi < 8; ++mi) {
        int row0 = bm0 + wm * 128 + mi * 16 + (lane >> 4) * 4;
        float sr[4];
#pragma unroll
        for (int rr = 0; rr < 4; ++rr) sr[rr] = srow[row0 + rr];
#pragma unroll
        for (int nj = 0; nj < 4; ++nj) {
            int col  = bn0 + wn * 64 + nj * 16 + (lane & 15);
            float sc = scales[col];
            float bv = bias[col];
#pragma unroll
            for (int rr = 0; rr < 4; ++rr)
                __builtin_nontemporal_store(
                    (float)acc[mi][nj][rr] * (sr[rr] * sc) + bv,
                    &out[(size_t)(row0 + rr) * OUT_F + col]);
        }
    }
}

// ---------- fallback (ws too small): reg-staged bf16 128^2 with inline dequant ----------
#define FBM 128
#define FBN 128
#define FTM (M_DIM / FBM)
#define FTN (OUT_F / FBN)
#define FNWG (FTM * FTN)

__global__ __launch_bounds__(256) void w4a16_gemm_fb(
    const float* __restrict__ xf,
    const int* __restrict__ pw,
    const float* __restrict__ scales, const int* __restrict__ zps,
    const float* __restrict__ bias, float* __restrict__ out) {

    __shared__ __align__(16) __bf16 As[FBM * 64];
    __shared__ __align__(16) __bf16 Bs[FBN * 64];

    const int tid  = threadIdx.x;
    const int lane = tid & 63;
    const int wid  = tid >> 6;
    const int wm   = wid >> 1;
    const int wn   = wid & 1;

    int orig = blockIdx.x;
    int wg   = (orig & 7) * (FNWG / 8) + (orig >> 3);
    const int bm0 = (wg / FTN) * FBM;
    const int bn0 = (wg % FTN) * FBN;

    f32x4 acc[4][4];
#pragma unroll
    for (int i = 0; i < 4; ++i)
#pragma unroll
        for (int j = 0; j < 4; ++j) acc[i][j] = {0.f, 0.f, 0.f, 0.f};

    for (int kt = 0; kt < IN_F / 64; ++kt) {
#pragma unroll
        for (int i = 0; i < 4; ++i) {
            int ci  = i * 256 + tid;
            int row = ci >> 3, c8 = ci & 7;
            const float4* pp = (const float4*)(xf + (size_t)(bm0 + row) * IN_F + kt * 64 + c8 * 8);
            uint4 d = pack8_f(pp[0], pp[1]);
            *(uint4*)((char*)As + row * 128 + ((c8 * 16) ^ ((row & 7) << 4))) = d;
        }
#pragma unroll
        for (int i = 0; i < 4; ++i) {
            int ci  = i * 256 + tid;
            int row = ci >> 3, c8 = ci & 7;
            int r    = bn0 + row;
            float s  = scales[r];
            float zb = -s * (float)zps[r];
            int4 v = *(const int4*)(pw + (size_t)r * (IN_F / 2) + kt * 32 + c8 * 4);
            uint4 d = dequant8(v, s, zb);
            *(uint4*)((char*)Bs + row * 128 + ((c8 * 16) ^ ((row & 7) << 4))) = d;
        }
        __syncthreads();

#pragma unroll
        for (int kk = 0; kk < 2; ++kk) {
            short8 a[4], b[4];
#pragma unroll
            for (int mi = 0; mi < 4; ++mi) {
                int row = wm * 64 + mi * 16 + (lane & 15);
                a[mi] = *(const short8*)((const char*)As + row * 128 +
                                         ((kk * 64 + (lane >> 4) * 16) ^ ((row & 7) << 4)));
            }
#pragma unroll
            for (int ni = 0; ni < 4; ++ni) {
                int row = wn * 64 + ni * 16 + (lane & 15);
                b[ni] = *(const short8*)((const char*)Bs + row * 128 +
                                         ((kk * 64 + (lane >> 4) * 16) ^ ((row & 7) << 4)));
            }
#pragma unroll
            for (int mi = 0; mi < 4; ++mi)
#pragma unroll
                for (int ni = 0; ni < 4; ++ni)
                    acc[mi][ni] = __builtin_amdgcn_mfma_f32_16x16x32_bf16(a[mi], b[ni], acc[mi][ni], 0, 0, 0);
        }
        __syncthreads();
    }

#pragma unroll
    for (int ni = 0; ni < 4; ++ni) {
        int col  = bn0 + wn * 64 + ni * 16 + (lane & 15);
        float bv = bias[col];
#pragma unroll
        for (int mi = 0; mi < 4; ++mi) {
            int row0 = bm0 + wm * 64 + mi * 16 + (lane >> 4) * 4;
#pragma unroll
            for (int r = 0; r < 4; ++r)
                out[(size_t)(row0 + r) * OUT_F + col] = acc[mi][ni][r] + bv;
        }
    }
}

extern "C" void kernel_launch(void* const* d_in, const int* in_sizes, int n_in,
                              void* d_out, int out_size, void* d_ws, size_t ws_size,
                              hipStream_t stream) {
    const float* x      = (const float*)d_in[0];
    const int* pw       = (const int*)d_in[1];
    const float* scales = (const float*)d_in[2];
    const int* zps      = (const int*)d_in[3];
    const float* bias   = (const float*)d_in[4];
    float* out          = (float*)d_out;

    const size_t xq_bytes = (size_t)M_DIM * IN_F;        // 32 MiB i8
    const size_t sr_bytes = 65536;                       // srow f32 + pad
    const size_t wq_bytes = (size_t)OUT_F * IN_F;        // ~43 MiB i8
    const bool predeq = ws_size >= xq_bytes + sr_bytes + wq_bytes;

    if (predeq) {
        char*  xq   = (char*)d_ws;
        float* srow = (float*)((char*)d_ws + xq_bytes);
        char*  wq   = (char*)d_ws + xq_bytes + sr_bytes;
        quant_x_kernel<<<dim3(M_DIM), dim3(256), 0, stream>>>(x, xq, srow);
        deqw_i8_kernel<<<dim3(2048), dim3(256), 0, stream>>>(pw, zps, wq, OUT_F * (IN_F / 16));
        (void)hipFuncSetAttribute((const void*)w4a16_gemm_i8,
                                  hipFuncAttributeMaxDynamicSharedMemorySize, 3 * TILE_B);
        w4a16_gemm_i8<<<dim3(NWG), dim3(256), 3 * TILE_B, stream>>>(
            (const uint4*)xq, (const uint4*)wq, srow, scales, bias, out);
    } else {
        w4a16_gemm_fb<<<dim3(FNWG), dim3(256), 0, stream>>>(x, pw, scales, zps, bias, out);
    }
}